// Round 11
// baseline (1990.022 us; speedup 1.0000x reference)
//
#include <hip/hip_runtime.h>
#include <hip/hip_fp16.h>

// ---------------------------------------------------------------------------
// Streaming causal-TCN decoder, round 10: MFMA conv engine (resubmit).
//  - Skeleton identical to round 9 (64 WGs x 512 thr, rings, 19 phases,
//    no-vmcnt-drain bar(), one-phase-ahead weight prefetch into P/Q sets).
//  - Convs/matmuls via v_mfma_f32_16x16x32_f16, M=1 (batch row broadcast):
//    A-frag addr depends only on lane>>4 -> all 16 A-rows equal -> every lane
//    holds out[ch] in acc[0]. Residuals live entirely in registers.
//  - Activations f16 in LDS (halves DS reads); weights f16 B-frag layout.
// ---------------------------------------------------------------------------

typedef _Float16 f16;
typedef __attribute__((ext_vector_type(8))) _Float16 f16x8;
typedef __attribute__((ext_vector_type(4))) float f32x4;
#define MFMA16(a, b, c) __builtin_amdgcn_mfma_f32_16x16x32_f16((a), (b), (c), 0, 0, 0)

// ---- f16 weight workspace layout (offsets in halfs) ----
// B-frag rows: one (nt, kk) row = 64 lanes x 8 halfs = 512 halfs.
// element (nt, kk, l, e) = w[k = kmap(kk, l>>4, e)][ch = nt*16 + (l&15)]
constexpr int OFF_WIN  = 0;       // 8nt x 6kk rows  (K=3x64, ci<33 else 0) = 24576
constexpr int OFF_WRES = 24576;   // 8nt x 2kk rows  (K=64, ci<33 else 0)   = 8192
constexpr int OFF_W1   = 32768;   // 7 convs x (8nt x 12kk) = 7 x 49152
constexpr int OFF_W2   = 376832;  // 8 convs x 49152
constexpr int OFF_WD0  = 770048;  // 8nt x 8kk rows  (K=256 = [h|enc])      = 32768
constexpr int OFF_WD1  = 802816;  // 4nt x 4kk rows  (K=128, N=64)          = 8192
constexpr int OFF_WD2  = 811008;  // 64
constexpr int WS_HALFS = 811072;

// ---- LDS (halfs) ----
constexpr int H_CURX = 0;      // 64 (33 used, zero pad)
constexpr int H_ENC  = 64;     // 128
constexpr int H_H0   = 192;    // 128
constexpr int H_H1   = 320;    // 128
constexpr int H_C1A  = 448;    // 128
constexpr int H_C1B  = 576;    // 128
constexpr int H_O1   = 704;    // 128
constexpr int H_IN0  = 832;    // 2 x 64 ring
// IN rings blk1..7 (depth 2*d x 128), MID rings blk0..7:
constexpr int INO[8]  = {0, 960, 1472, 2496, 4544, 4800, 5312, 6336};
constexpr int MIDO[8] = {8384, 8640, 9152, 10176, 12224, 12480, 12992, 14016};
constexpr int SMH_HALFS = 16064;  // 32128 B
constexpr int DIL[8] = {1, 2, 4, 8, 1, 2, 4, 8};

__device__ __forceinline__ float elu1(float x) { return x > 0.f ? x : expm1f(x); }

// Barrier WITHOUT the vmcnt(0) drain __syncthreads() would emit (round-9 win).
__device__ __forceinline__ void bar() {
    __builtin_amdgcn_sched_barrier(0);
    asm volatile("s_waitcnt lgkmcnt(0)" ::: "memory");
    __builtin_amdgcn_s_barrier();
    __builtin_amdgcn_sched_barrier(0);
}

struct W12 { f16x8 v[12]; };

template <int N>
__device__ __forceinline__ void loadWn(W12& w, const f16* __restrict__ p) {
#pragma unroll
    for (int j = 0; j < N; ++j) w.v[j] = *(const f16x8*)(p + j * 512);
}
__device__ __forceinline__ void loadS0(W12& w, const f16* __restrict__ wsh, int nt, int lane) {
    const f16* p1 = wsh + OFF_WIN + nt * 3072 + lane * 8;
#pragma unroll
    for (int j = 0; j < 6; ++j) w.v[j] = *(const f16x8*)(p1 + j * 512);
    const f16* p2 = wsh + OFF_WRES + nt * 1024 + lane * 8;
#pragma unroll
    for (int j = 0; j < 2; ++j) w.v[6 + j] = *(const f16x8*)(p2 + j * 512);
}

// K=3 128->128 conv: kk 0-3 = x[t-2d], 4-7 = x[t-d], 8-11 = x[t]
__device__ __forceinline__ void conv12(f32x4& acc, const W12& w, const f16* smh,
                                       int b2d, int b1d, int b0, int g8) {
#pragma unroll
    for (int kk = 0; kk < 12; ++kk) {
        int base = (kk < 4) ? b2d : (kk < 8 ? b1d : b0);
        f16x8 a = *(const f16x8*)(smh + base + (kk & 3) * 32 + g8);
        acc = MFMA16(a, w.v[kk], acc);
    }
}

// ---------------------------------------------------------------------------
// prep kernel: fp32 -> f16 B-fragment layout
// ---------------------------------------------------------------------------
__global__ void prep_weights(const float* __restrict__ w_in, const float* __restrict__ w_res,
                             const float* __restrict__ w1, const float* __restrict__ w2,
                             const float* __restrict__ wd0, const float* __restrict__ wd1,
                             const float* __restrict__ wd2, f16* __restrict__ dst) {
    int i = blockIdx.x * blockDim.x + threadIdx.x;
    if (i >= WS_HALFS) return;
    float v = 0.f;
    if (i < OFF_WRES) {
        int e = i & 7, l = (i >> 3) & 63, r = i >> 9;            // r = nt*6+kk
        int kk = r % 6, nt = r / 6;
        int tap = kk >> 1, ci = (kk & 1) * 32 + ((l >> 4) << 3) + e, ch = nt * 16 + (l & 15);
        v = (ci < 33) ? w_in[(tap * 33 + ci) * 128 + ch] : 0.f;
    } else if (i < OFF_W1) {
        int q = i - OFF_WRES, e = q & 7, l = (q >> 3) & 63, r = q >> 9;  // r = nt*2+kk
        int kk = r & 1, nt = r >> 1;
        int ci = kk * 32 + ((l >> 4) << 3) + e, ch = nt * 16 + (l & 15);
        v = (ci < 33) ? w_res[ci * 128 + ch] : 0.f;
    } else if (i < OFF_W2) {
        int q = i - OFF_W1, bb = q / 49152, s = q % 49152;
        int e = s & 7, l = (s >> 3) & 63, r = s >> 9;            // r = nt*12+kk
        int kk = r % 12, nt = r / 12;
        int tap = kk >> 2, ci = (kk & 3) * 32 + ((l >> 4) << 3) + e, ch = nt * 16 + (l & 15);
        v = w1[((size_t)(bb * 3 + tap) * 128 + ci) * 128 + ch];
    } else if (i < OFF_WD0) {
        int q = i - OFF_W2, bb = q / 49152, s = q % 49152;
        int e = s & 7, l = (s >> 3) & 63, r = s >> 9;
        int kk = r % 12, nt = r / 12;
        int tap = kk >> 2, ci = (kk & 3) * 32 + ((l >> 4) << 3) + e, ch = nt * 16 + (l & 15);
        v = w2[((size_t)(bb * 3 + tap) * 128 + ci) * 128 + ch];
    } else if (i < OFF_WD1) {
        int q = i - OFF_WD0, e = q & 7, l = (q >> 3) & 63, r = q >> 9;   // r = nt*8+kk
        int kk = r & 7, nt = r >> 3;
        int ci = kk * 32 + ((l >> 4) << 3) + e;                  // 0..255 = [h|enc]
        v = wd0[ci * 128 + nt * 16 + (l & 15)];
    } else if (i < OFF_WD2) {
        int q = i - OFF_WD1, e = q & 7, l = (q >> 3) & 63, r = q >> 9;   // r = nt*4+kk
        int kk = r & 3, nt = r >> 2;
        int ci = kk * 32 + ((l >> 4) << 3) + e, ch = nt * 16 + (l & 15); // ch < 64
        v = wd1[ci * 64 + ch];
    } else {
        v = wd2[i - OFF_WD2];
    }
    dst[i] = (f16)v;
}

// ---------------------------------------------------------------------------
// main kernel
// ---------------------------------------------------------------------------
__global__ __launch_bounds__(512) void decoder_stream(
    const float* __restrict__ enc, const float* __restrict__ dec,
    const float* __restrict__ last_y, const f16* __restrict__ wsh,
    const float* __restrict__ b_in, const float* __restrict__ b_res,
    const float* __restrict__ b1, const float* __restrict__ b2,
    const float* __restrict__ bd0, const float* __restrict__ bd1,
    const float* __restrict__ bd2, const float* __restrict__ wd2,
    float* __restrict__ out) {
    __shared__ f16 smh[SMH_HALFS];
    __shared__ float smf[64];
    const int tid = threadIdx.x;
    const int b = blockIdx.x;
    const int lane = tid & 63;
    const int nt = tid >> 6;                 // wave = n-tile (16 ch)
    const int g8 = ((lane >> 4) << 3);       // k-subgroup offset (halfs)
    const int ch = nt * 16 + (lane & 15);    // this lane's output channel

    // zero all LDS halfs (rings + CURX pad must be 0)
    for (int i = tid; i < SMH_HALFS / 2; i += 512) ((unsigned int*)smh)[i] = 0u;
    __syncthreads();
    if (tid < 128) smh[H_ENC + tid] = (f16)enc[((size_t)b * 128 + 127) * 128 + tid];
    if (tid < 32) smh[H_CURX + tid] = (f16)dec[(size_t)b * 32 * 32 + tid];
    if (tid == 32) smh[H_CURX + 32] = (f16)last_y[b];
    __syncthreads();

    // bias / head-weight preload (per-lane, registers)
    const float rb_in = b_in[ch], rb_res = b_res[ch], rbd0 = bd0[ch];
    const float rbd1 = bd1[ch & 63];
    float rb1[7], rb2[8];
#pragma unroll
    for (int j = 0; j < 7; ++j) rb1[j] = b1[j * 128 + ch];
#pragma unroll
    for (int j = 0; j < 8; ++j) rb2[j] = b2[j * 128 + ch];
    const float wd2r = (tid < 64) ? wd2[tid] : 0.f;
    const float bd2v = bd2[0];

    W12 P, Q;
    loadS0(P, wsh, nt, lane);  // S0 weights for t=0
    float hreg = 0.f, resreg = 0.f;

#pragma unroll 1
    for (int t = 0; t < 32; ++t) {
        // ---------- S0: conv_in + res-1x1 (input CURX, 64-pad) ----------
        {
            loadWn<12>(Q, wsh + OFF_W2 + nt * 6144 + lane * 8);  // prefetch conv2(blk0)
            const int a2d = H_IN0 + (t & 1) * 64;        // x[t-2]
            const int a1d = H_IN0 + ((t - 1) & 1) * 64;  // x[t-1]
            f32x4 aC = {0.f, 0.f, 0.f, 0.f}, aR = {0.f, 0.f, 0.f, 0.f};
#pragma unroll
            for (int kk = 0; kk < 6; ++kk) {
                int base = (kk < 2) ? a2d : (kk < 4 ? a1d : H_CURX);
                f16x8 a = *(const f16x8*)(smh + base + (kk & 1) * 32 + g8);
                aC = MFMA16(a, P.v[kk], aC);
            }
#pragma unroll
            for (int kk = 0; kk < 2; ++kk) {
                f16x8 a = *(const f16x8*)(smh + H_CURX + kk * 32 + g8);
                aR = MFMA16(a, P.v[6 + kk], aR);
            }
            float c1 = elu1(aC[0] + rb_in);
            resreg = aR[0] + rb_res;                    // residual stays in regs
            if (lane < 16) smh[H_C1A + ch] = (f16)c1;
            bar();
        }
        // ---------- S1: conv2(blk0) d=1, + residual ----------
        {
            loadWn<12>(P, wsh + OFF_W1 + nt * 6144 + lane * 8);  // prefetch conv1(blk1)
            if (tid < 64) smh[H_IN0 + (t & 1) * 64 + tid] = smh[H_CURX + tid];  // push IN0
            f32x4 acc = {0.f, 0.f, 0.f, 0.f};
            conv12(acc, Q, smh, MIDO[0] + (t & 1) * 128, MIDO[0] + ((t - 1) & 1) * 128,
                   H_C1A, g8);
            float v = elu1(acc[0] + rb2[0]);
            hreg = elu1(v + resreg);
            if (lane < 16) smh[H_H1 + ch] = (f16)hreg;
            bar();
        }
        // ---------- blocks 1..7 (fully unrolled: static biases/offsets) ----------
#pragma unroll
        for (int blk = 1; blk < 8; ++blk) {
            const int d = DIL[blk], m = 2 * d;
            const int mprev = 2 * DIL[blk - 1];
            const int p = blk & 1;
            const int Hp = p ? H_H1 : H_H0, Hq = p ? H_H0 : H_H1;
            const int C1p = p ? H_C1B : H_C1A, C1q = p ? H_C1A : H_C1B;
            // conv1: uses P; prefetch Q = conv2(blk)
            {
                loadWn<12>(Q, wsh + OFF_W2 + blk * 49152 + nt * 6144 + lane * 8);
                if (tid < 128)  // push MID[blk-1] <- c1 of previous block
                    smh[MIDO[blk - 1] + (t & (mprev - 1)) * 128 + tid] = smh[C1q + tid];
                f32x4 acc = {0.f, 0.f, 0.f, 0.f};
                conv12(acc, P, smh, INO[blk] + (t & (m - 1)) * 128,
                       INO[blk] + ((t - d) & (m - 1)) * 128, Hp, g8);
                float c1 = elu1(acc[0] + rb1[blk - 1]);
                if (lane < 16) smh[C1p + ch] = (f16)c1;
                bar();
            }
            // conv2: uses Q; prefetch P = conv1(blk+1) or d0
            {
                if (blk < 7) loadWn<12>(P, wsh + OFF_W1 + blk * 49152 + nt * 6144 + lane * 8);
                else loadWn<8>(P, wsh + OFF_WD0 + nt * 4096 + lane * 8);
                if (tid < 128)  // push IN[blk] <- h (block input)
                    smh[INO[blk] + (t & (m - 1)) * 128 + tid] = smh[Hp + tid];
                f32x4 acc = {0.f, 0.f, 0.f, 0.f};
                conv12(acc, Q, smh, MIDO[blk] + (t & (m - 1)) * 128,
                       MIDO[blk] + ((t - d) & (m - 1)) * 128, C1p, g8);
                float v = elu1(acc[0] + rb2[blk]);
                hreg = elu1(v + hreg);                  // residual = block input (regs)
                if (lane < 16) smh[Hq + ch] = (f16)hreg;
                bar();
            }
        }
        // ---------- d0: [h | enc] -> O1 ----------
        {
            loadWn<4>(Q, wsh + OFF_WD1 + (nt & 3) * 2048 + lane * 8);  // prefetch d1
            if (tid < 128)  // push MID[7] (16-deep) <- c1 of blk7 (C1B)
                smh[MIDO[7] + (t & 15) * 128 + tid] = smh[H_C1B + tid];
            f32x4 acc = {0.f, 0.f, 0.f, 0.f};
#pragma unroll
            for (int kk = 0; kk < 8; ++kk) {
                int base = (kk < 4) ? (H_H0 + kk * 32) : (H_ENC + (kk - 4) * 32);
                f16x8 a = *(const f16x8*)(smh + base + g8);
                acc = MFMA16(a, P.v[kk], acc);
            }
            float v = elu1(acc[0] + rbd0);
            if (lane < 16) smh[H_O1 + ch] = (f16)v;
            bar();
        }
        // ---------- d1: O1 -> O2(f32); stage next dec row; prefetch S0 ----------
        {
            loadS0(P, wsh, nt, lane);
            if (nt < 4) {
                f32x4 acc = {0.f, 0.f, 0.f, 0.f};
#pragma unroll
                for (int kk = 0; kk < 4; ++kk) {
                    f16x8 a = *(const f16x8*)(smh + H_O1 + kk * 32 + g8);
                    acc = MFMA16(a, Q.v[kk], acc);
                }
                float v = elu1(acc[0] + rbd1);
                if (lane < 16) smf[ch] = v;            // ch < 64
            }
            int tn = t < 31 ? t + 1 : 31;
            if (tid < 32) smh[H_CURX + tid] = (f16)dec[((size_t)b * 32 + tn) * 32 + tid];
            bar();
        }
        // ---------- d2: O2 -> pred ----------
        if (tid < 64) {
            float v = smf[tid] * wd2r;
#pragma unroll
            for (int off = 32; off; off >>= 1) v += __shfl_xor(v, off, 64);
            if (tid == 0) {
                float pr = v + bd2v;
                out[b * 32 + t] = pr;
                smh[H_CURX + 32] = (f16)pr;
            }
        }
        bar();
    }
}

extern "C" void kernel_launch(void* const* d_in, const int* in_sizes, int n_in,
                              void* d_out, int out_size, void* d_ws, size_t ws_size,
                              hipStream_t stream) {
    const float* enc    = (const float*)d_in[0];
    const float* dec    = (const float*)d_in[1];
    const float* last_y = (const float*)d_in[2];
    const float* w_in   = (const float*)d_in[3];
    const float* b_in   = (const float*)d_in[4];
    const float* w_res  = (const float*)d_in[5];
    const float* b_res  = (const float*)d_in[6];
    const float* w1     = (const float*)d_in[7];
    const float* b1     = (const float*)d_in[8];
    const float* w2     = (const float*)d_in[9];
    const float* b2     = (const float*)d_in[10];
    const float* wd0    = (const float*)d_in[11];
    const float* bd0    = (const float*)d_in[12];
    const float* wd1    = (const float*)d_in[13];
    const float* bd1    = (const float*)d_in[14];
    const float* wd2    = (const float*)d_in[15];
    const float* bd2    = (const float*)d_in[16];
    float* out = (float*)d_out;
    f16* wsh = (f16*)d_ws;

    prep_weights<<<(WS_HALFS + 255) / 256, 256, 0, stream>>>(w_in, w_res, w1, w2, wd0, wd1,
                                                             wd2, wsh);
    decoder_stream<<<64, 512, 0, stream>>>(enc, dec, last_y, wsh, b_in, b_res, b1, b2, bd0,
                                           bd1, bd2, wd2, out);
}